// Round 1
// baseline (281.500 us; speedup 1.0000x reference)
//
#include <hip/hip_runtime.h>
#include <math.h>

// Problem constants (from reference): B=2, C=64, E=4, HLR=WLR=192, scale=2 -> H=W=384
#define HLR_ 192
#define WLR_ 192
#define H_ 384
#define W_ 384
#define LRP (HLR_*WLR_)            // 36864 LR pixels per (b,c)
#define PTILES (LRP/64)            // 576
#define WTILES (W_/64)             // 6

// ws layout (floats):
//   [0 .. 4718592)                 fused_t  [B][HLR][WLR][C]
//   [4718592 .. +2048)             wc_mix   [4 cls][8 o][64 c]
//   [+2048 .. +4096)               weT_mix  [4 cls][8 o][64 c]  (= we[c][o] transposed)
//   [+4096 .. +4104)               offsets  [4 cls][2]
#define WS_MIX_OFF 4718592

// ---------------------------------------------------------------------------
// Kernel A: per-class (parity) MLP -> routing/offset -> mixed expert weights.
// Exactly 4 classes exist for scale=2; fp32 values are bit-identical to
// per-pixel evaluation (coor_h/w = +-0.25 exactly).
// ---------------------------------------------------------------------------
__global__ __launch_bounds__(256) void precompute_kernel(
    const float* __restrict__ w1, const float* __restrict__ b1,
    const float* __restrict__ w2, const float* __restrict__ b2,
    const float* __restrict__ rw, const float* __restrict__ rb,
    const float* __restrict__ ow, const float* __restrict__ ob,
    const float* __restrict__ WC, const float* __restrict__ WE,
    float* __restrict__ g_mix, float* __restrict__ g_off)
{
    __shared__ float sW2[64*65];   // padded to kill bank conflicts
    __shared__ float sE1[4][64];
    __shared__ float sE2[4][64];
    __shared__ float sR[4][4];

    int tid = threadIdx.x;
    for (int idx = tid; idx < 4096; idx += 256) {
        int o = idx >> 6, i = idx & 63;
        sW2[o*65 + i] = w2[idx];
    }
    int wave = tid >> 6, lane = tid & 63;   // wave == class = ph*2 + pw
    int ph = wave >> 1, pw = wave & 1;

    float ch = (ph + 0.5f) * 0.5f;
    float coor_h = ch - floorf(ch + 0.001f) - 0.5f;
    float cw = (pw + 0.5f) * 0.5f;
    float coor_w = cw - floorf(cw + 0.001f) - 0.5f;

    float e1 = w1[lane*4+0]*0.5f + w1[lane*4+1]*0.5f
             + w1[lane*4+2]*coor_h + w1[lane*4+3]*coor_w + b1[lane];
    e1 = fmaxf(e1, 0.0f);
    sE1[wave][lane] = e1;
    __syncthreads();

    float acc = b2[lane];
    #pragma unroll 16
    for (int i = 0; i < 64; ++i) acc += sW2[lane*65 + i] * sE1[wave][i];
    acc = fmaxf(acc, 0.0f);
    sE2[wave][lane] = acc;
    __syncthreads();

    if (lane < 6) {
        int k = lane;
        float a = (k < 4) ? rb[k] : ob[k-4];
        const float* wv = (k < 4) ? (rw + k*64) : (ow + (k-4)*64);
        for (int i = 0; i < 64; ++i) a += wv[i] * sE2[wave][i];
        if (k < 4) sR[wave][k] = 1.0f / (1.0f + expf(-a));
        else       g_off[wave*2 + (k-4)] = a;
    }
    __syncthreads();

    // mixed weights: idx in [0,4096): half(1b) | cls(2b) | o(3b) | c(6b)
    for (int idx = tid; idx < 4096; idx += 256) {
        int half = idx >> 11;
        int rem  = idx & 2047;
        int cls  = rem >> 9;
        int rem2 = rem & 511;
        int o = rem2 >> 6, c = rem2 & 63;
        float r0 = sR[cls][0], r1 = sR[cls][1], r2 = sR[cls][2], r3 = sR[cls][3];
        float v;
        if (half == 0) {  // wc[o][c] = sum_e r_e * WC[e][o][c]
            v = r0*WC[0*512 + rem2] + r1*WC[1*512 + rem2]
              + r2*WC[2*512 + rem2] + r3*WC[3*512 + rem2];
        } else {          // weT[o][c] = sum_e r_e * WE[e][c][o]
            int src = c*8 + o;
            v = r0*WE[0*512 + src] + r1*WE[1*512 + src]
              + r2*WE[2*512 + src] + r3*WE[3*512 + src];
        }
        g_mix[idx] = v;
    }
}

// ---------------------------------------------------------------------------
// Kernel B: transpose fused [B][C][HLR][WLR] -> fused_t [B][HLR*WLR][C]
// ---------------------------------------------------------------------------
__global__ __launch_bounds__(256) void transpose_kernel(
    const float* __restrict__ fused, float* __restrict__ fused_t)
{
    __shared__ float tile[64][65];
    int bid = blockIdx.x;
    int b = bid / PTILES, pt = bid % PTILES;
    int p0 = pt * 64;
    int tid = threadIdx.x;
    int tlo = tid & 63, thi = tid >> 6;
    #pragma unroll
    for (int i = 0; i < 16; ++i) {
        int c = thi + i*4;
        tile[c][tlo] = fused[(size_t)(b*64 + c)*LRP + p0 + tlo];
    }
    __syncthreads();
    #pragma unroll
    for (int i = 0; i < 16; ++i) {
        int p = thi + i*4;
        fused_t[(size_t)(b*LRP + p0 + p)*64 + tlo] = tile[tlo][p];
    }
}

// ---------------------------------------------------------------------------
// Kernel C: main. One block = 64 pixels of one HR row (both batches).
// Wave-per-pixel, lane = channel. Wave's w-parity is fixed (w steps by 4),
// so mixed weights live in registers, loaded once per wave.
// ---------------------------------------------------------------------------
__global__ __launch_bounds__(256) void main_kernel(
    const float* __restrict__ fused_t, const float* __restrict__ g_mix,
    const float* __restrict__ g_off, float* __restrict__ out)
{
    __shared__ float sWC[2][512];       // [pw][o*64+c]
    __shared__ float sWE[2][512];
    __shared__ float sOut[2][64*65];    // [b][c*65 + wl]

    int bid = blockIdx.x;
    int h = bid / WTILES, wt = bid % WTILES;
    int w0 = wt << 6;
    int ph = h & 1;
    int tid = threadIdx.x;

    for (int idx = tid; idx < 1024; idx += 256) {
        int pw = idx >> 9, rem = idx & 511;
        sWC[pw][rem] = g_mix[(ph*2 + pw)*512 + rem];
        sWE[pw][rem] = g_mix[2048 + (ph*2 + pw)*512 + rem];
    }
    __syncthreads();

    int wave = tid >> 6, lane = tid & 63;
    int pw = wave & 1;

    float wcx[8], wet[8];
    #pragma unroll
    for (int o = 0; o < 8; ++o) {
        wcx[o] = sWC[pw][o*64 + lane];
        wet[o] = sWE[pw][o*64 + lane];
    }
    float off0 = g_off[(ph*2 + pw)*2 + 0];
    float off1 = g_off[(ph*2 + pw)*2 + 1];

    // row-constant y quantities
    float py  = (h + 0.5f)*0.5f - 0.5f + off1;
    float y0f = floorf(py);
    float wy  = py - y0f;
    int   y0  = (int)y0f;
    bool  vy0 = (y0f >= 0.0f) && (y0f <= (float)(HLR_-1));
    bool  vy1 = (y0f + 1.0f >= 0.0f) && (y0f + 1.0f <= (float)(HLR_-1));
    int   yc0 = min(max(y0, 0), HLR_-1);
    int   yc1 = min(max(y0+1, 0), HLR_-1);
    float omwy = 1.0f - wy;

    for (int i = 0; i < 16; ++i) {
        int wl = wave + i*4;
        int w  = w0 + wl;
        float px  = (w + 0.5f)*0.5f - 0.5f + off0;
        float x0f = floorf(px);
        float wx  = px - x0f;
        int   x0  = (int)x0f;
        bool  vx0 = (x0f >= 0.0f) && (x0f <= (float)(WLR_-1));
        bool  vx1 = (x0f + 1.0f >= 0.0f) && (x0f + 1.0f <= (float)(WLR_-1));
        int   xc0 = min(max(x0, 0), WLR_-1);
        int   xc1 = min(max(x0+1, 0), WLR_-1);
        float m00 = (vx0 && vy0) ? 1.0f : 0.0f;
        float m01 = (vx1 && vy0) ? 1.0f : 0.0f;
        float m10 = (vx0 && vy1) ? 1.0f : 0.0f;
        float m11 = (vx1 && vy1) ? 1.0f : 0.0f;
        float omwx = 1.0f - wx;

        #pragma unroll
        for (int b = 0; b < 2; ++b) {
            const float* base = fused_t + (size_t)b * LRP * 64;
            const float* r0 = base + (size_t)(yc0 * WLR_) * 64;
            const float* r1 = base + (size_t)(yc1 * WLR_) * 64;
            float v00 = r0[xc0*64 + lane] * m00;
            float v01 = r0[xc1*64 + lane] * m01;
            float v10 = r1[xc0*64 + lane] * m10;
            float v11 = r1[xc1*64 + lane] * m11;
            float top = v00*omwx + v01*wx;
            float bot = v10*omwx + v11*wx;
            float fea = top*omwy + bot*wy;

            float p[8];
            #pragma unroll
            for (int o = 0; o < 8; ++o) p[o] = wcx[o] * fea;
            #pragma unroll
            for (int m = 1; m <= 32; m <<= 1) {
                #pragma unroll
                for (int o = 0; o < 8; ++o) p[o] += __shfl_xor(p[o], m, 64);
            }
            float ov = fea;
            #pragma unroll
            for (int o = 0; o < 8; ++o) ov += wet[o] * p[o];
            sOut[b][lane*65 + wl] = ov;
        }
    }
    __syncthreads();

    #pragma unroll
    for (int k = 0; k < 32; ++k) {
        int idx = tid + k*256;
        int b = idx >> 12;
        int rem = idx & 4095;
        int c = rem >> 6, wq = rem & 63;
        out[((size_t)(b*64 + c)*H_ + h)*W_ + w0 + wq] = sOut[b][c*65 + wq];
    }
}

extern "C" void kernel_launch(void* const* d_in, const int* in_sizes, int n_in,
                              void* d_out, int out_size, void* d_ws, size_t ws_size,
                              hipStream_t stream)
{
    // setup_inputs order: x, fused, weight_compress, weight_expand, body_w1,
    // body_b1, body_w2, body_b2, routing_w, routing_b, offset_w, offset_b, scale
    const float* fused = (const float*)d_in[1];
    const float* WC    = (const float*)d_in[2];
    const float* WE    = (const float*)d_in[3];
    const float* w1    = (const float*)d_in[4];
    const float* b1    = (const float*)d_in[5];
    const float* w2    = (const float*)d_in[6];
    const float* b2    = (const float*)d_in[7];
    const float* rw    = (const float*)d_in[8];
    const float* rb    = (const float*)d_in[9];
    const float* ow    = (const float*)d_in[10];
    const float* ob    = (const float*)d_in[11];
    (void)in_sizes; (void)n_in; (void)out_size; (void)ws_size;

    float* ws      = (float*)d_ws;
    float* fused_t = ws;
    float* g_mix   = ws + WS_MIX_OFF;
    float* g_off   = g_mix + 4096;
    float* o       = (float*)d_out;

    hipLaunchKernelGGL(precompute_kernel, dim3(1), dim3(256), 0, stream,
                       w1, b1, w2, b2, rw, rb, ow, ob, WC, WE, g_mix, g_off);
    hipLaunchKernelGGL(transpose_kernel, dim3(2*PTILES), dim3(256), 0, stream,
                       fused, fused_t);
    hipLaunchKernelGGL(main_kernel, dim3(H_*WTILES), dim3(256), 0, stream,
                       fused_t, g_mix, g_off, o);
}

// Round 2
// 164.633 us; speedup vs baseline: 1.7099x; 1.7099x over previous
//
#include <hip/hip_runtime.h>
#include <math.h>

typedef __attribute__((ext_vector_type(8))) short short8;
typedef __attribute__((ext_vector_type(4))) float f32x4;

// Problem constants: B=2, C=64, E=4, HLR=WLR=192, scale=2 -> H=W=384
#define HLR_ 192
#define WLR_ 192
#define H_ 384
#define W_ 384
#define LRP (HLR_*WLR_)            // 36864
#define PTILES (LRP/64)            // 576
#define TPX 128                    // pixels per main block
#define NTW (W_/TPX)               // 3

// ws layout (float units):
//   [0 .. 4718592)            fused_t [B][HLR*WLR][C] fp32
//   [4718592 .. +8192)        Kmat: 4 cls x 64 x 64 bf16 (16384 ushorts)
//   then 8 floats             g_off [4 cls][2]
#define WS_K_OFF 4718592
#define WS_OFF_OFF (WS_K_OFF + 8192)

__device__ __forceinline__ unsigned short f32_bf16(float x){
    union { float f; unsigned int u; } v; v.f = x;
    unsigned int r = v.u + 0x7fffu + ((v.u >> 16) & 1u);
    return (unsigned short)(r >> 16);
}
__device__ __forceinline__ float bf16_f32(unsigned short h){
    union { float f; unsigned int u; } v; v.u = ((unsigned int)h) << 16;
    return v.f;
}

// ---------------------------------------------------------------------------
// Kernel A: per-class MLP -> routing/offset -> fused K = weT_mix @ wc_mix
// (bf16), plus per-class offsets. Everything staged in LDS; no serial
// global-latency loops.
// ---------------------------------------------------------------------------
__global__ __launch_bounds__(256) void precompute_kernel(
    const float* __restrict__ w1, const float* __restrict__ b1,
    const float* __restrict__ w2, const float* __restrict__ b2,
    const float* __restrict__ rw, const float* __restrict__ rb,
    const float* __restrict__ ow, const float* __restrict__ ob,
    const float* __restrict__ WC, const float* __restrict__ WE,
    unsigned short* __restrict__ Kmat, float* __restrict__ g_off)
{
    __shared__ float sW2[64*65];
    __shared__ float sRW[6*64];     // routing_w rows 0-3, offset_w rows 4-5
    __shared__ float sE1[4][64];
    __shared__ float sR[4][4];
    __shared__ float sWc[4][8][64];
    __shared__ float sWe[4][64][8];

    int tid = threadIdx.x;
    for (int idx = tid; idx < 4096; idx += 256)
        sW2[(idx>>6)*65 + (idx&63)] = w2[idx];
    if (tid < 256) sRW[tid] = rw[tid];
    if (tid < 128) sRW[256 + tid] = ow[tid];

    int wave = tid >> 6, lane = tid & 63;   // wave = class = ph*2 + pw
    int ph = wave >> 1, pw = wave & 1;

    float ch = (ph + 0.5f)*0.5f;
    float coor_h = ch - floorf(ch + 0.001f) - 0.5f;
    float cw = (pw + 0.5f)*0.5f;
    float coor_w = cw - floorf(cw + 0.001f) - 0.5f;

    float e1 = w1[lane*4+0]*0.5f + w1[lane*4+1]*0.5f
             + w1[lane*4+2]*coor_h + w1[lane*4+3]*coor_w + b1[lane];
    sE1[wave][lane] = fmaxf(e1, 0.0f);
    __syncthreads();

    float e2 = b2[lane];
    #pragma unroll 16
    for (int i = 0; i < 64; ++i) e2 += sW2[lane*65 + i] * sE1[wave][i];
    e2 = fmaxf(e2, 0.0f);

    #pragma unroll
    for (int k = 0; k < 6; ++k) {
        float t = sRW[k*64 + lane] * e2;
        #pragma unroll
        for (int m = 1; m <= 32; m <<= 1) t += __shfl_xor(t, m, 64);
        if (lane == 0) {
            if (k < 4) sR[wave][k] = 1.0f/(1.0f + expf(-(t + rb[k])));
            else       g_off[wave*2 + (k-4)] = t + ob[k-4];
        }
    }
    __syncthreads();

    for (int idx = tid; idx < 2048; idx += 256) {
        int cls = idx >> 9, rem = idx & 511;          // rem = o*64 + c
        float r0=sR[cls][0], r1=sR[cls][1], r2=sR[cls][2], r3=sR[cls][3];
        sWc[cls][rem>>6][rem&63] =
            r0*WC[0*512+rem] + r1*WC[1*512+rem] + r2*WC[2*512+rem] + r3*WC[3*512+rem];
    }
    for (int idx = tid; idx < 2048; idx += 256) {
        int cls = idx >> 9, rem = idx & 511;          // rem = c*8 + o
        float r0=sR[cls][0], r1=sR[cls][1], r2=sR[cls][2], r3=sR[cls][3];
        sWe[cls][rem>>3][rem&7] =
            r0*WE[0*512+rem] + r1*WE[1*512+rem] + r2*WE[2*512+rem] + r3*WE[3*512+rem];
    }
    __syncthreads();

    // K[cls][c][cp] = sum_o we[c][o] * wc[o][cp]   (A-matrix for MFMA, bf16)
    for (int idx = tid; idx < 16384; idx += 256) {
        int cls = idx >> 12, rem = idx & 4095;
        int c = rem >> 6, cp = rem & 63;
        float a = 0.0f;
        #pragma unroll
        for (int o = 0; o < 8; ++o) a += sWe[cls][c][o] * sWc[cls][o][cp];
        Kmat[idx] = f32_bf16(a);
    }
}

// ---------------------------------------------------------------------------
// Kernel B: transpose fused [B][C][HLR][WLR] -> fused_t [B][HLR*WLR][C]
// ---------------------------------------------------------------------------
__global__ __launch_bounds__(256) void transpose_kernel(
    const float* __restrict__ fused, float* __restrict__ fused_t)
{
    __shared__ float tile[64][65];
    int bid = blockIdx.x;
    int b = bid / PTILES, pt = bid % PTILES;
    int p0 = pt * 64;
    int tid = threadIdx.x;
    int tlo = tid & 63, thi = tid >> 6;
    #pragma unroll
    for (int i = 0; i < 16; ++i) {
        int c = thi + i*4;
        tile[c][tlo] = fused[(size_t)(b*64 + c)*LRP + p0 + tlo];
    }
    __syncthreads();
    #pragma unroll
    for (int i = 0; i < 16; ++i) {
        int p = thi + i*4;
        fused_t[(size_t)(b*LRP + p0 + p)*64 + tlo] = tile[tlo][p];
    }
}

// ---------------------------------------------------------------------------
// Kernel C: main. Block = 128 HR pixels of one row x 2 batches (256 items).
// Wave w = (batch = w>>1, parity = w&1): 64 same-class items.
// Phase 1 (lane=c): bilinear gather -> sFea bf16 [item][72].
// Phase 2: per-wave 64x64 = K_cls(A) @ feaT(B) via 32 MFMA; epilogue adds
// identity (fea) and stores directly.
// ---------------------------------------------------------------------------
__global__ __launch_bounds__(256, 2) void main_kernel(
    const float* __restrict__ fused_t, const unsigned short* __restrict__ Kmat,
    const float* __restrict__ g_off, float* __restrict__ out)
{
    __shared__ unsigned short sFea[256*72];   // 36.9 KB, pitch 72 (16B-aligned rows)

    int bid = blockIdx.x;
    int h = bid / NTW, wt = bid % NTW;
    int w0 = wt * TPX;
    int tid = threadIdx.x, wave = tid >> 6, lane = tid & 63;
    int b = wave >> 1, par = wave & 1;
    int ph = h & 1, cls = ph*2 + par;

    float off0 = g_off[cls*2 + 0];
    float off1 = g_off[cls*2 + 1];

    // y quantities: wave-uniform
    float py  = (h + 0.5f)*0.5f - 0.5f + off1;
    float y0f = floorf(py);
    float wy  = py - y0f;
    int   y0  = (int)y0f;
    float fy0 = (y0 >= 0  && y0 <= HLR_-1) ? 1.0f : 0.0f;
    float fy1 = (y0 >= -1 && y0 <= HLR_-2) ? 1.0f : 0.0f;
    int   yc0 = min(max(y0, 0), HLR_-1);
    int   yc1 = min(max(y0+1, 0), HLR_-1);
    float omwy = 1.0f - wy;

    // x: px for item i (pixel w = w0 + 2i + par) = pxb + i exactly -> wx uniform
    float pxb  = (w0 + par + 0.5f)*0.5f - 0.5f + off0;
    float x0bf = floorf(pxb);
    float wx   = pxb - x0bf;
    int   x0b  = (int)x0bf;
    float omwx = 1.0f - wx;

    const float* baseB = fused_t + (size_t)b * LRP * 64;
    const float* r0 = baseB + (size_t)yc0 * WLR_ * 64;
    const float* r1 = baseB + (size_t)yc1 * WLR_ * 64;
    unsigned short* sRow = sFea + wave*64*72;

    #pragma unroll 8
    for (int i = 0; i < 64; ++i) {
        int x0 = x0b + i;
        float fx0 = (x0 >= 0  && x0 <= WLR_-1) ? 1.0f : 0.0f;
        float fx1 = (x0 >= -1 && x0 <= WLR_-2) ? 1.0f : 0.0f;
        int xc0 = min(max(x0, 0), WLR_-1);
        int xc1 = min(max(x0+1, 0), WLR_-1);
        float w00 = omwx*omwy*fx0*fy0;
        float w01 = wx  *omwy*fx1*fy0;
        float w10 = omwx*wy  *fx0*fy1;
        float w11 = wx  *wy  *fx1*fy1;
        float v = r0[xc0*64 + lane]*w00 + r0[xc1*64 + lane]*w01
                + r1[xc0*64 + lane]*w10 + r1[xc1*64 + lane]*w11;
        sRow[i*72 + lane] = f32_bf16(v);
    }
    __syncthreads();

    // ---- phase 2 ----
    int lm = lane & 15, lg = lane >> 4;

    short8 Bf[2][4];   // B[k][n]: n = item slot, from sFea rows (k contiguous)
    #pragma unroll
    for (int nt = 0; nt < 4; ++nt)
        #pragma unroll
        for (int kt = 0; kt < 2; ++kt)
            Bf[kt][nt] = *(const short8*)(sFea + (wave*64 + nt*16 + lm)*72 + kt*32 + lg*8);

    const unsigned short* Kc = Kmat + cls*4096;
    short8 Af[4][2];   // A[m][k]: m = out channel
    #pragma unroll
    for (int mt = 0; mt < 4; ++mt)
        #pragma unroll
        for (int kt = 0; kt < 2; ++kt)
            Af[mt][kt] = *(const short8*)(Kc + (mt*16 + lm)*64 + kt*32 + lg*8);

    f32x4 acc[4][4];
    #pragma unroll
    for (int mt = 0; mt < 4; ++mt) {
        #pragma unroll
        for (int nt = 0; nt < 4; ++nt) {
            f32x4 a = {0.0f, 0.0f, 0.0f, 0.0f};
            a = __builtin_amdgcn_mfma_f32_16x16x32_bf16(Af[mt][0], Bf[0][nt], a, 0, 0, 0);
            a = __builtin_amdgcn_mfma_f32_16x16x32_bf16(Af[mt][1], Bf[1][nt], a, 0, 0, 0);
            acc[mt][nt] = a;
        }
    }

    // epilogue: D[row=c][col=item]; col=lane&15, row=(lane>>4)*4+reg (m89 map)
    #pragma unroll
    for (int mt = 0; mt < 4; ++mt) {
        #pragma unroll
        for (int nt = 0; nt < 4; ++nt) {
            int slot = wave*64 + nt*16 + lm;
            ushort4 idv = *(const ushort4*)(sFea + slot*72 + mt*16 + lg*4);
            int wc = w0 + 2*(nt*16 + lm) + par;
            int c0 = mt*16 + lg*4;
            float* op = out + (((size_t)(b*64 + c0)*H_ + h)*W_ + wc);
            op[0*(size_t)(H_*W_)] = acc[mt][nt][0] + bf16_f32(idv.x);
            op[1*(size_t)(H_*W_)] = acc[mt][nt][1] + bf16_f32(idv.y);
            op[2*(size_t)(H_*W_)] = acc[mt][nt][2] + bf16_f32(idv.z);
            op[3*(size_t)(H_*W_)] = acc[mt][nt][3] + bf16_f32(idv.w);
        }
    }
}

extern "C" void kernel_launch(void* const* d_in, const int* in_sizes, int n_in,
                              void* d_out, int out_size, void* d_ws, size_t ws_size,
                              hipStream_t stream)
{
    const float* fused = (const float*)d_in[1];
    const float* WC    = (const float*)d_in[2];
    const float* WE    = (const float*)d_in[3];
    const float* w1    = (const float*)d_in[4];
    const float* b1    = (const float*)d_in[5];
    const float* w2    = (const float*)d_in[6];
    const float* b2    = (const float*)d_in[7];
    const float* rw    = (const float*)d_in[8];
    const float* rb    = (const float*)d_in[9];
    const float* ow    = (const float*)d_in[10];
    const float* ob    = (const float*)d_in[11];
    (void)in_sizes; (void)n_in; (void)out_size; (void)ws_size;

    float* ws = (float*)d_ws;
    float* fused_t = ws;
    unsigned short* Kmat = (unsigned short*)(ws + WS_K_OFF);
    float* g_off = ws + WS_OFF_OFF;
    float* o = (float*)d_out;

    hipLaunchKernelGGL(precompute_kernel, dim3(1), dim3(256), 0, stream,
                       w1, b1, w2, b2, rw, rb, ow, ob, WC, WE, Kmat, g_off);
    hipLaunchKernelGGL(transpose_kernel, dim3(2*PTILES), dim3(256), 0, stream,
                       fused, fused_t);
    hipLaunchKernelGGL(main_kernel, dim3(H_*NTW), dim3(256), 0, stream,
                       fused_t, Kmat, g_off, o);
}

// Round 3
// 155.769 us; speedup vs baseline: 1.8072x; 1.0569x over previous
//
#include <hip/hip_runtime.h>
#include <math.h>

typedef __attribute__((ext_vector_type(8))) short short8;
typedef __attribute__((ext_vector_type(4))) float f32x4;

// Problem constants: B=2, C=64, E=4, HLR=WLR=192, scale=2 -> H=W=384
#define HLR_ 192
#define WLR_ 192
#define H_ 384
#define W_ 384
#define LRP (HLR_*WLR_)            // 36864
#define PTILES (LRP/64)            // 576
#define TPX 128                    // pixels per main block
#define NTW (W_/TPX)               // 3

// ws layout (float units):
//   [0 .. 4718592)            fused_t [B][HLR*WLR][C] fp32
//   [4718592 .. +8192)        Kmat: 4 cls x 64 x 64 bf16 (16384 ushorts)
//   then 8 floats             g_off [4 cls][2]
#define WS_K_OFF 4718592
#define WS_OFF_OFF (WS_K_OFF + 8192)

__device__ __forceinline__ unsigned short f32_bf16(float x){
    union { float f; unsigned int u; } v; v.f = x;
    unsigned int r = v.u + 0x7fffu + ((v.u >> 16) & 1u);
    return (unsigned short)(r >> 16);
}
__device__ __forceinline__ float bf16_f32(unsigned short h){
    union { float f; unsigned int u; } v; v.u = ((unsigned int)h) << 16;
    return v.f;
}

// ---------------------------------------------------------------------------
// Kernel A: per-class MLP -> routing/offset -> fused K = weT_mix @ wc_mix
// (bf16), plus per-class offsets.
// ---------------------------------------------------------------------------
__global__ __launch_bounds__(256) void precompute_kernel(
    const float* __restrict__ w1, const float* __restrict__ b1,
    const float* __restrict__ w2, const float* __restrict__ b2,
    const float* __restrict__ rw, const float* __restrict__ rb,
    const float* __restrict__ ow, const float* __restrict__ ob,
    const float* __restrict__ WC, const float* __restrict__ WE,
    unsigned short* __restrict__ Kmat, float* __restrict__ g_off)
{
    __shared__ float sW2[64*65];
    __shared__ float sRW[6*64];     // routing_w rows 0-3, offset_w rows 4-5
    __shared__ float sE1[4][64];
    __shared__ float sR[4][4];
    __shared__ float sWc[4][8][64];
    __shared__ float sWe[4][64][8];

    int tid = threadIdx.x;
    for (int idx = tid; idx < 4096; idx += 256)
        sW2[(idx>>6)*65 + (idx&63)] = w2[idx];
    if (tid < 256) sRW[tid] = rw[tid];
    if (tid < 128) sRW[256 + tid] = ow[tid];

    int wave = tid >> 6, lane = tid & 63;   // wave = class = ph*2 + pw
    int ph = wave >> 1, pw = wave & 1;

    float ch = (ph + 0.5f)*0.5f;
    float coor_h = ch - floorf(ch + 0.001f) - 0.5f;
    float cw = (pw + 0.5f)*0.5f;
    float coor_w = cw - floorf(cw + 0.001f) - 0.5f;

    float e1 = w1[lane*4+0]*0.5f + w1[lane*4+1]*0.5f
             + w1[lane*4+2]*coor_h + w1[lane*4+3]*coor_w + b1[lane];
    sE1[wave][lane] = fmaxf(e1, 0.0f);
    __syncthreads();

    float e2 = b2[lane];
    #pragma unroll 16
    for (int i = 0; i < 64; ++i) e2 += sW2[lane*65 + i] * sE1[wave][i];
    e2 = fmaxf(e2, 0.0f);

    #pragma unroll
    for (int k = 0; k < 6; ++k) {
        float t = sRW[k*64 + lane] * e2;
        #pragma unroll
        for (int m = 1; m <= 32; m <<= 1) t += __shfl_xor(t, m, 64);
        if (lane == 0) {
            if (k < 4) sR[wave][k] = 1.0f/(1.0f + expf(-(t + rb[k])));
            else       g_off[wave*2 + (k-4)] = t + ob[k-4];
        }
    }
    __syncthreads();

    for (int idx = tid; idx < 2048; idx += 256) {
        int cls = idx >> 9, rem = idx & 511;          // rem = o*64 + c
        float r0=sR[cls][0], r1=sR[cls][1], r2=sR[cls][2], r3=sR[cls][3];
        sWc[cls][rem>>6][rem&63] =
            r0*WC[0*512+rem] + r1*WC[1*512+rem] + r2*WC[2*512+rem] + r3*WC[3*512+rem];
    }
    for (int idx = tid; idx < 2048; idx += 256) {
        int cls = idx >> 9, rem = idx & 511;          // rem = c*8 + o
        float r0=sR[cls][0], r1=sR[cls][1], r2=sR[cls][2], r3=sR[cls][3];
        sWe[cls][rem>>3][rem&7] =
            r0*WE[0*512+rem] + r1*WE[1*512+rem] + r2*WE[2*512+rem] + r3*WE[3*512+rem];
    }
    __syncthreads();

    // K[cls][c][cp] = sum_o we[c][o] * wc[o][cp]   (A-matrix for MFMA, bf16)
    for (int idx = tid; idx < 16384; idx += 256) {
        int cls = idx >> 12, rem = idx & 4095;
        int c = rem >> 6, cp = rem & 63;
        float a = 0.0f;
        #pragma unroll
        for (int o = 0; o < 8; ++o) a += sWe[cls][c][o] * sWc[cls][o][cp];
        Kmat[idx] = f32_bf16(a);
    }
}

// ---------------------------------------------------------------------------
// Kernel B: transpose fused [B][C][HLR][WLR] -> fused_t [B][HLR*WLR][C]
// ---------------------------------------------------------------------------
__global__ __launch_bounds__(256) void transpose_kernel(
    const float* __restrict__ fused, float* __restrict__ fused_t)
{
    __shared__ float tile[64][65];
    int bid = blockIdx.x;
    int b = bid / PTILES, pt = bid % PTILES;
    int p0 = pt * 64;
    int tid = threadIdx.x;
    int tlo = tid & 63, thi = tid >> 6;
    #pragma unroll
    for (int i = 0; i < 16; ++i) {
        int c = thi + i*4;
        tile[c][tlo] = fused[(size_t)(b*64 + c)*LRP + p0 + tlo];
    }
    __syncthreads();
    #pragma unroll
    for (int i = 0; i < 16; ++i) {
        int p = thi + i*4;
        fused_t[(size_t)(b*LRP + p0 + p)*64 + tlo] = tile[tlo][p];
    }
}

// ---------------------------------------------------------------------------
// Kernel C: main. Block = 128 HR pixels of one row x 2 batches (256 items).
// Wave w = (batch = w>>1, parity = w&1): 64 same-class items.
// Phase 1 (lane = item-subgroup x channel-quad): vectorized bilinear gather
//   4 x global_load_dwordx4 + 1 x ds_write_b64 per iter, 16 iters.
// Phase 2: per-wave 64x64 = K_cls(A) @ feaT(B) via 32 MFMA; epilogue adds
// identity (fea) and stores directly.
// XCD swizzle: each XCD (blockIdx&7) owns 48 consecutive h rows -> LR rows
// stay L2-resident (~2.6 MB < 4 MB).
// ---------------------------------------------------------------------------
__global__ __launch_bounds__(256, 4) void main_kernel(
    const float* __restrict__ fused_t, const unsigned short* __restrict__ Kmat,
    const float* __restrict__ g_off, float* __restrict__ out)
{
    __shared__ unsigned short sFea[256*72];   // 36.9 KB, pitch 72 ushorts (144B)

    int g = blockIdx.x;
    int xcd = g & 7;
    int t = g >> 3;                 // 0..143
    int q = t / 3;                  // 0..47
    int wt = t - q*3;
    int h = xcd*48 + q;
    int w0 = wt * TPX;
    int tid = threadIdx.x, wave = tid >> 6, lane = tid & 63;
    int b = wave >> 1, par = wave & 1;
    int ph = h & 1, cls = ph*2 + par;

    float off0 = g_off[cls*2 + 0];
    float off1 = g_off[cls*2 + 1];

    // y quantities: wave-uniform
    float py  = (h + 0.5f)*0.5f - 0.5f + off1;
    float y0f = floorf(py);
    float wy  = py - y0f;
    int   y0  = (int)y0f;
    float fy0 = (y0 >= 0  && y0 <= HLR_-1) ? 1.0f : 0.0f;
    float fy1 = (y0 >= -1 && y0 <= HLR_-2) ? 1.0f : 0.0f;
    int   yc0 = min(max(y0, 0), HLR_-1);
    int   yc1 = min(max(y0+1, 0), HLR_-1);
    float omwy = 1.0f - wy;

    // x: px for item i (pixel w = w0 + 2i + par) = pxb + i exactly -> wx uniform
    float pxb  = (w0 + par + 0.5f)*0.5f - 0.5f + off0;
    float x0bf = floorf(pxb);
    float wx   = pxb - x0bf;
    int   x0b  = (int)x0bf;
    float omwx = 1.0f - wx;

    // wave-uniform corner weights with y-masks folded in
    float W00 = omwx*omwy*fy0, W01 = wx*omwy*fy0;
    float W10 = omwx*wy  *fy1, W11 = wx*wy  *fy1;

    int itg = lane >> 4;            // item subgroup 0..3
    int cg  = lane & 15;            // channel quad

    const float* baseB = fused_t + (size_t)b * LRP * 64;
    const float* r0 = baseB + (size_t)yc0 * WLR_ * 64 + cg*4;
    const float* r1 = baseB + (size_t)yc1 * WLR_ * 64 + cg*4;
    unsigned short* sW = sFea + wave*64*72 + cg*4;

    #pragma unroll
    for (int j = 0; j < 16; ++j) {
        int item = j*4 + itg;
        int x0 = x0b + item;
        float fx0 = (x0 >= 0  && x0 <= WLR_-1) ? 1.0f : 0.0f;
        float fx1 = (x0 >= -1 && x0 <= WLR_-2) ? 1.0f : 0.0f;
        int xc0 = min(max(x0, 0), WLR_-1);
        int xc1 = min(max(x0+1, 0), WLR_-1);
        float a00 = W00*fx0, a01 = W01*fx1, a10 = W10*fx0, a11 = W11*fx1;
        f32x4 v00 = *(const f32x4*)(r0 + (size_t)xc0*64);
        f32x4 v01 = *(const f32x4*)(r0 + (size_t)xc1*64);
        f32x4 v10 = *(const f32x4*)(r1 + (size_t)xc0*64);
        f32x4 v11 = *(const f32x4*)(r1 + (size_t)xc1*64);
        f32x4 v = v00*a00 + v01*a01 + v10*a10 + v11*a11;
        ushort4 u;
        u.x = f32_bf16(v[0]); u.y = f32_bf16(v[1]);
        u.z = f32_bf16(v[2]); u.w = f32_bf16(v[3]);
        *(ushort4*)(sW + item*72) = u;
    }
    __syncthreads();

    // ---- phase 2 ----
    int lm = lane & 15, lg = lane >> 4;

    short8 Bf[2][4];   // B[k][n]: n = item slot
    #pragma unroll
    for (int nt = 0; nt < 4; ++nt)
        #pragma unroll
        for (int kt = 0; kt < 2; ++kt)
            Bf[kt][nt] = *(const short8*)(sFea + (wave*64 + nt*16 + lm)*72 + kt*32 + lg*8);

    const unsigned short* Kc = Kmat + cls*4096;
    short8 Af[4][2];   // A[m][k]: m = out channel
    #pragma unroll
    for (int mt = 0; mt < 4; ++mt)
        #pragma unroll
        for (int kt = 0; kt < 2; ++kt)
            Af[mt][kt] = *(const short8*)(Kc + (mt*16 + lm)*64 + kt*32 + lg*8);

    f32x4 acc[4][4];
    #pragma unroll
    for (int mt = 0; mt < 4; ++mt) {
        #pragma unroll
        for (int nt = 0; nt < 4; ++nt) {
            f32x4 a = {0.0f, 0.0f, 0.0f, 0.0f};
            a = __builtin_amdgcn_mfma_f32_16x16x32_bf16(Af[mt][0], Bf[0][nt], a, 0, 0, 0);
            a = __builtin_amdgcn_mfma_f32_16x16x32_bf16(Af[mt][1], Bf[1][nt], a, 0, 0, 0);
            acc[mt][nt] = a;
        }
    }

    // epilogue: D[row=c][col=item]; col=lane&15, row=(lane>>4)*4+reg (m89 map)
    #pragma unroll
    for (int mt = 0; mt < 4; ++mt) {
        #pragma unroll
        for (int nt = 0; nt < 4; ++nt) {
            int slot = wave*64 + nt*16 + lm;
            ushort4 idv = *(const ushort4*)(sFea + slot*72 + mt*16 + lg*4);
            int wc = w0 + 2*(nt*16 + lm) + par;
            int c0 = mt*16 + lg*4;
            float* op = out + (((size_t)(b*64 + c0)*H_ + h)*W_ + wc);
            op[0*(size_t)(H_*W_)] = acc[mt][nt][0] + bf16_f32(idv.x);
            op[1*(size_t)(H_*W_)] = acc[mt][nt][1] + bf16_f32(idv.y);
            op[2*(size_t)(H_*W_)] = acc[mt][nt][2] + bf16_f32(idv.z);
            op[3*(size_t)(H_*W_)] = acc[mt][nt][3] + bf16_f32(idv.w);
        }
    }
}

extern "C" void kernel_launch(void* const* d_in, const int* in_sizes, int n_in,
                              void* d_out, int out_size, void* d_ws, size_t ws_size,
                              hipStream_t stream)
{
    const float* fused = (const float*)d_in[1];
    const float* WC    = (const float*)d_in[2];
    const float* WE    = (const float*)d_in[3];
    const float* w1    = (const float*)d_in[4];
    const float* b1    = (const float*)d_in[5];
    const float* w2    = (const float*)d_in[6];
    const float* b2    = (const float*)d_in[7];
    const float* rw    = (const float*)d_in[8];
    const float* rb    = (const float*)d_in[9];
    const float* ow    = (const float*)d_in[10];
    const float* ob    = (const float*)d_in[11];
    (void)in_sizes; (void)n_in; (void)out_size; (void)ws_size;

    float* ws = (float*)d_ws;
    float* fused_t = ws;
    unsigned short* Kmat = (unsigned short*)(ws + WS_K_OFF);
    float* g_off = ws + WS_OFF_OFF;
    float* o = (float*)d_out;

    hipLaunchKernelGGL(precompute_kernel, dim3(1), dim3(256), 0, stream,
                       w1, b1, w2, b2, rw, rb, ow, ob, WC, WE, Kmat, g_off);
    hipLaunchKernelGGL(transpose_kernel, dim3(2*PTILES), dim3(256), 0, stream,
                       fused, fused_t);
    hipLaunchKernelGGL(main_kernel, dim3(H_*NTW), dim3(256), 0, stream,
                       fused_t, Kmat, g_off, o);
}

// Round 4
// 150.484 us; speedup vs baseline: 1.8706x; 1.0351x over previous
//
#include <hip/hip_runtime.h>
#include <hip/hip_bf16.h>
#include <math.h>

typedef __attribute__((ext_vector_type(8))) short short8;
typedef __attribute__((ext_vector_type(4))) float f32x4;

// Problem constants: B=2, C=64, E=4, HLR=WLR=192, scale=2 -> H=W=384
#define HLR_ 192
#define WLR_ 192
#define H_ 384
#define W_ 384
#define LRP (HLR_*WLR_)            // 36864
#define PTILES (LRP/64)            // 576
#define TPX 128                    // pixels per main block
#define NTW (W_/TPX)               // 3

// ws layout (float units):
//   [0 .. 4718592)            fused_t [B][HLR*WLR][C] fp32
//   [4718592 .. +8192)        Kmat: 4 cls x 64 x 64 bf16 (16384 ushorts), K' = I + weT@wc
//   then 8 floats             g_off [4 cls][2]
#define WS_K_OFF 4718592
#define WS_OFF_OFF (WS_K_OFF + 8192)

__device__ __forceinline__ unsigned short f32_bf16(float x){
    union { float f; unsigned int u; } v; v.f = x;
    unsigned int r = v.u + 0x7fffu + ((v.u >> 16) & 1u);
    return (unsigned short)(r >> 16);
}
__device__ __forceinline__ unsigned int pk_bf16(float a, float b){
    float2 t; t.x = a; t.y = b;
    __hip_bfloat162 h = __float22bfloat162_rn(t);
    union { __hip_bfloat162 h; unsigned int u; } c; c.h = h;
    return c.u;
}

// ---------------------------------------------------------------------------
// Kernel A (merged): block 0 = precompute (per-class MLP -> routing/offset ->
// K' = I + weT_mix@wc_mix in bf16); blocks 1.. = transpose
// fused [B][C][HLR][WLR] -> fused_t [B][HLR*WLR][C].
// ---------------------------------------------------------------------------
__global__ __launch_bounds__(256) void prep_kernel(
    const float* __restrict__ fused, float* __restrict__ fused_t,
    const float* __restrict__ w1, const float* __restrict__ b1,
    const float* __restrict__ w2, const float* __restrict__ b2,
    const float* __restrict__ rw, const float* __restrict__ rb,
    const float* __restrict__ ow, const float* __restrict__ ob,
    const float* __restrict__ WC, const float* __restrict__ WE,
    unsigned short* __restrict__ Kmat, float* __restrict__ g_off)
{
    __shared__ float smem[8912];    // 35.6 KB, unioned between the two paths
    int bid = blockIdx.x;
    int tid = threadIdx.x;

    if (bid == 0) {
        float* sW2 = smem;          // [64][65] = 4160
        float* sRW = smem + 4160;   // [6][64]  = 384
        float* sE1 = smem + 4544;   // [4][64]  = 256
        float* sR  = smem + 4800;   // [4][4]   = 16
        float* sWc = smem + 4816;   // [4][8][64]  = 2048
        float* sWe = smem + 6864;   // [4][64][8]  = 2048

        for (int idx = tid; idx < 4096; idx += 256)
            sW2[(idx>>6)*65 + (idx&63)] = w2[idx];
        sRW[tid] = rw[tid];
        if (tid < 128) sRW[256 + tid] = ow[tid];

        int wave = tid >> 6, lane = tid & 63;   // wave = class = ph*2 + pw
        int ph = wave >> 1, pw = wave & 1;

        float ch = (ph + 0.5f)*0.5f;
        float coor_h = ch - floorf(ch + 0.001f) - 0.5f;
        float cw = (pw + 0.5f)*0.5f;
        float coor_w = cw - floorf(cw + 0.001f) - 0.5f;

        float e1 = w1[lane*4+0]*0.5f + w1[lane*4+1]*0.5f
                 + w1[lane*4+2]*coor_h + w1[lane*4+3]*coor_w + b1[lane];
        sE1[wave*64 + lane] = fmaxf(e1, 0.0f);
        __syncthreads();

        float e2 = b2[lane];
        #pragma unroll 16
        for (int i = 0; i < 64; ++i) e2 += sW2[lane*65 + i] * sE1[wave*64 + i];
        e2 = fmaxf(e2, 0.0f);

        #pragma unroll
        for (int k = 0; k < 6; ++k) {
            float t = sRW[k*64 + lane] * e2;
            #pragma unroll
            for (int m = 1; m <= 32; m <<= 1) t += __shfl_xor(t, m, 64);
            if (lane == 0) {
                if (k < 4) sR[wave*4 + k] = 1.0f/(1.0f + expf(-(t + rb[k])));
                else       g_off[wave*2 + (k-4)] = t + ob[k-4];
            }
        }
        __syncthreads();

        for (int idx = tid; idx < 2048; idx += 256) {
            int cls = idx >> 9, rem = idx & 511;          // rem = o*64 + c
            float r0=sR[cls*4+0], r1=sR[cls*4+1], r2=sR[cls*4+2], r3=sR[cls*4+3];
            sWc[cls*512 + rem] =
                r0*WC[0*512+rem] + r1*WC[1*512+rem] + r2*WC[2*512+rem] + r3*WC[3*512+rem];
        }
        for (int idx = tid; idx < 2048; idx += 256) {
            int cls = idx >> 9, rem = idx & 511;          // rem = c*8 + o
            float r0=sR[cls*4+0], r1=sR[cls*4+1], r2=sR[cls*4+2], r3=sR[cls*4+3];
            sWe[cls*512 + rem] =
                r0*WE[0*512+rem] + r1*WE[1*512+rem] + r2*WE[2*512+rem] + r3*WE[3*512+rem];
        }
        __syncthreads();

        // K'[cls][c][cp] = (c==cp) + sum_o we[c][o]*wc[o][cp]  (identity folded)
        for (int idx = tid; idx < 16384; idx += 256) {
            int cls = idx >> 12, rem = idx & 4095;
            int c = rem >> 6, cp = rem & 63;
            float a = (c == cp) ? 1.0f : 0.0f;
            #pragma unroll
            for (int o = 0; o < 8; ++o)
                a += sWe[cls*512 + c*8 + o] * sWc[cls*512 + o*64 + cp];
            Kmat[idx] = f32_bf16(a);
        }
    } else {
        float* tile = smem;   // [64][65]
        int id = bid - 1;
        int b = id / PTILES, pt = id % PTILES;
        int p0 = pt * 64;
        int tlo = tid & 63, thi = tid >> 6;
        #pragma unroll
        for (int i = 0; i < 16; ++i) {
            int c = thi + i*4;
            tile[c*65 + tlo] = fused[(size_t)(b*64 + c)*LRP + p0 + tlo];
        }
        __syncthreads();
        #pragma unroll
        for (int i = 0; i < 16; ++i) {
            int p = thi + i*4;
            fused_t[(size_t)(b*LRP + p0 + p)*64 + tlo] = tile[tlo*65 + p];
        }
    }
}

// ---------------------------------------------------------------------------
// Kernel B: main. Block = 128 HR pixels of one row x 2 batches (256 items).
// Wave w = (batch = w>>1, parity = w&1): 64 same-class items.
// Phase 1 (lane = item-subgroup x channel-quad): vectorized bilinear gather
//   4 x global_load_dwordx4 + packed bf16 cvt + ds_write_b64, 16 iters.
// Phase 2: per-wave 64x64 = K'_cls(A) @ feaT(B) via 32 MFMA (identity folded
// into K'); direct stores.
// XCD swizzle: each XCD (blockIdx&7) owns 48 consecutive h rows.
// ---------------------------------------------------------------------------
__global__ __launch_bounds__(256, 4) void main_kernel(
    const float* __restrict__ fused_t, const unsigned short* __restrict__ Kmat,
    const float* __restrict__ g_off, float* __restrict__ out)
{
    __shared__ unsigned short sFea[256*72];   // 36.9 KB, pitch 72 ushorts (144B)

    int g = blockIdx.x;
    int xcd = g & 7;
    int t = g >> 3;                 // 0..143
    int q = t / 3;                  // 0..47
    int wt = t - q*3;
    int h = xcd*48 + q;
    int w0 = wt * TPX;
    int tid = threadIdx.x, wave = tid >> 6, lane = tid & 63;
    int b = wave >> 1, par = wave & 1;
    int ph = h & 1, cls = ph*2 + par;

    float off0 = g_off[cls*2 + 0];
    float off1 = g_off[cls*2 + 1];

    // y quantities: wave-uniform
    float py  = (h + 0.5f)*0.5f - 0.5f + off1;
    float y0f = floorf(py);
    float wy  = py - y0f;
    int   y0  = (int)y0f;
    float fy0 = (y0 >= 0  && y0 <= HLR_-1) ? 1.0f : 0.0f;
    float fy1 = (y0 >= -1 && y0 <= HLR_-2) ? 1.0f : 0.0f;
    int   yc0 = min(max(y0, 0), HLR_-1);
    int   yc1 = min(max(y0+1, 0), HLR_-1);
    float omwy = 1.0f - wy;

    // x: px for item i (pixel w = w0 + 2i + par) = pxb + i exactly -> wx uniform
    float pxb  = (w0 + par + 0.5f)*0.5f - 0.5f + off0;
    float x0bf = floorf(pxb);
    float wx   = pxb - x0bf;
    int   x0b  = (int)x0bf;
    float omwx = 1.0f - wx;

    // wave-uniform corner weights with y-masks folded in
    float W00 = omwx*omwy*fy0, W01 = wx*omwy*fy0;
    float W10 = omwx*wy  *fy1, W11 = wx*wy  *fy1;

    int itg = lane >> 4;            // item subgroup 0..3
    int cg  = lane & 15;            // channel quad

    const float* baseB = fused_t + (size_t)b * LRP * 64;
    const float* r0 = baseB + (size_t)yc0 * WLR_ * 64 + cg*4;
    const float* r1 = baseB + (size_t)yc1 * WLR_ * 64 + cg*4;
    unsigned short* sW = sFea + wave*64*72 + cg*4;

    #pragma unroll
    for (int j = 0; j < 16; ++j) {
        int item = j*4 + itg;
        int x0 = x0b + item;
        float fx0 = (x0 >= 0  && x0 <= WLR_-1) ? 1.0f : 0.0f;
        float fx1 = (x0 >= -1 && x0 <= WLR_-2) ? 1.0f : 0.0f;
        int xc0 = min(max(x0, 0), WLR_-1);
        int xc1 = min(max(x0+1, 0), WLR_-1);
        float a00 = W00*fx0, a01 = W01*fx1, a10 = W10*fx0, a11 = W11*fx1;
        f32x4 v00 = *(const f32x4*)(r0 + (size_t)xc0*64);
        f32x4 v01 = *(const f32x4*)(r0 + (size_t)xc1*64);
        f32x4 v10 = *(const f32x4*)(r1 + (size_t)xc0*64);
        f32x4 v11 = *(const f32x4*)(r1 + (size_t)xc1*64);
        f32x4 v = v00*a00 + v01*a01 + v10*a10 + v11*a11;
        uint2 pv;
        pv.x = pk_bf16(v[0], v[1]);
        pv.y = pk_bf16(v[2], v[3]);
        *(uint2*)(sW + item*72) = pv;
    }
    __syncthreads();

    // ---- phase 2 ----
    int lm = lane & 15, lg = lane >> 4;

    short8 Bf[2][4];   // B[k][n]: n = item slot
    #pragma unroll
    for (int nt = 0; nt < 4; ++nt)
        #pragma unroll
        for (int kt = 0; kt < 2; ++kt)
            Bf[kt][nt] = *(const short8*)(sFea + (wave*64 + nt*16 + lm)*72 + kt*32 + lg*8);

    const unsigned short* Kc = Kmat + cls*4096;
    short8 Af[4][2];   // A[m][k]: m = out channel
    #pragma unroll
    for (int mt = 0; mt < 4; ++mt)
        #pragma unroll
        for (int kt = 0; kt < 2; ++kt)
            Af[mt][kt] = *(const short8*)(Kc + (mt*16 + lm)*64 + kt*32 + lg*8);

    f32x4 acc[4][4];
    #pragma unroll
    for (int mt = 0; mt < 4; ++mt) {
        #pragma unroll
        for (int nt = 0; nt < 4; ++nt) {
            f32x4 a = {0.0f, 0.0f, 0.0f, 0.0f};
            a = __builtin_amdgcn_mfma_f32_16x16x32_bf16(Af[mt][0], Bf[0][nt], a, 0, 0, 0);
            a = __builtin_amdgcn_mfma_f32_16x16x32_bf16(Af[mt][1], Bf[1][nt], a, 0, 0, 0);
            acc[mt][nt] = a;
        }
    }

    // epilogue: D[row=c][col=item]; col=lane&15, row=(lane>>4)*4+reg (m89 map)
    #pragma unroll
    for (int mt = 0; mt < 4; ++mt) {
        #pragma unroll
        for (int nt = 0; nt < 4; ++nt) {
            int wc = w0 + 2*(nt*16 + lm) + par;
            int c0 = mt*16 + lg*4;
            float* op = out + (((size_t)(b*64 + c0)*H_ + h)*W_ + wc);
            op[0*(size_t)(H_*W_)] = acc[mt][nt][0];
            op[1*(size_t)(H_*W_)] = acc[mt][nt][1];
            op[2*(size_t)(H_*W_)] = acc[mt][nt][2];
            op[3*(size_t)(H_*W_)] = acc[mt][nt][3];
        }
    }
}

extern "C" void kernel_launch(void* const* d_in, const int* in_sizes, int n_in,
                              void* d_out, int out_size, void* d_ws, size_t ws_size,
                              hipStream_t stream)
{
    const float* fused = (const float*)d_in[1];
    const float* WC    = (const float*)d_in[2];
    const float* WE    = (const float*)d_in[3];
    const float* w1    = (const float*)d_in[4];
    const float* b1    = (const float*)d_in[5];
    const float* w2    = (const float*)d_in[6];
    const float* b2    = (const float*)d_in[7];
    const float* rw    = (const float*)d_in[8];
    const float* rb    = (const float*)d_in[9];
    const float* ow    = (const float*)d_in[10];
    const float* ob    = (const float*)d_in[11];
    (void)in_sizes; (void)n_in; (void)out_size; (void)ws_size;

    float* ws = (float*)d_ws;
    float* fused_t = ws;
    unsigned short* Kmat = (unsigned short*)(ws + WS_K_OFF);
    float* g_off = ws + WS_OFF_OFF;
    float* o = (float*)d_out;

    hipLaunchKernelGGL(prep_kernel, dim3(1 + 2*PTILES), dim3(256), 0, stream,
                       fused, fused_t, w1, b1, w2, b2, rw, rb, ow, ob, WC, WE,
                       Kmat, g_off);
    hipLaunchKernelGGL(main_kernel, dim3(H_*NTW), dim3(256), 0, stream,
                       fused_t, Kmat, g_off, o);
}

// Round 5
// 149.016 us; speedup vs baseline: 1.8891x; 1.0099x over previous
//
#include <hip/hip_runtime.h>
#include <hip/hip_bf16.h>
#include <math.h>

typedef __attribute__((ext_vector_type(8))) short short8;
typedef __attribute__((ext_vector_type(4))) float f32x4;

// Problem constants: B=2, C=64, E=4, HLR=WLR=192, scale=2 -> H=W=384
#define HLR_ 192
#define WLR_ 192
#define H_ 384
#define W_ 384
#define LRP (HLR_*WLR_)            // 36864
#define PTILES (LRP/64)            // 576
#define TPX 96                     // pixels per main block (4 tiles/row)
#define NTW (W_/TPX)               // 4
#define IPW 48                     // items per wave (TPX/2 parities)

// ws layout (float units):
//   [0 .. 4718592)            fused_t [B][HLR*WLR][C] fp32
//   [4718592 .. +8192)        Kmat: 4 cls x 64 x 64 bf16, K' = I + weT@wc
//   then 8 floats             g_off [4 cls][2]
#define WS_K_OFF 4718592
#define WS_OFF_OFF (WS_K_OFF + 8192)

__device__ __forceinline__ unsigned short f32_bf16(float x){
    union { float f; unsigned int u; } v; v.f = x;
    unsigned int r = v.u + 0x7fffu + ((v.u >> 16) & 1u);
    return (unsigned short)(r >> 16);
}
__device__ __forceinline__ unsigned int pk_bf16(float a, float b){
    float2 t; t.x = a; t.y = b;
    __hip_bfloat162 h = __float22bfloat162_rn(t);
    union { __hip_bfloat162 h; unsigned int u; } c; c.h = h;
    return c.u;
}

// ---------------------------------------------------------------------------
// Kernel A (merged): block 0 = precompute (per-class MLP -> routing/offset ->
// K' = I + weT_mix@wc_mix in bf16); blocks 1.. = transpose
// fused [B][C][HLR][WLR] -> fused_t [B][HLR*WLR][C].
// ---------------------------------------------------------------------------
__global__ __launch_bounds__(256) void prep_kernel(
    const float* __restrict__ fused, float* __restrict__ fused_t,
    const float* __restrict__ w1, const float* __restrict__ b1,
    const float* __restrict__ w2, const float* __restrict__ b2,
    const float* __restrict__ rw, const float* __restrict__ rb,
    const float* __restrict__ ow, const float* __restrict__ ob,
    const float* __restrict__ WC, const float* __restrict__ WE,
    unsigned short* __restrict__ Kmat, float* __restrict__ g_off)
{
    __shared__ float smem[8912];    // 35.6 KB, unioned between the two paths
    int bid = blockIdx.x;
    int tid = threadIdx.x;

    if (bid == 0) {
        float* sW2 = smem;          // [64][65] = 4160
        float* sRW = smem + 4160;   // [6][64]  = 384
        float* sE1 = smem + 4544;   // [4][64]  = 256
        float* sR  = smem + 4800;   // [4][4]   = 16
        float* sWc = smem + 4816;   // [4][8][64]  = 2048
        float* sWe = smem + 6864;   // [4][64][8]  = 2048

        for (int idx = tid; idx < 4096; idx += 256)
            sW2[(idx>>6)*65 + (idx&63)] = w2[idx];
        sRW[tid] = rw[tid];
        if (tid < 128) sRW[256 + tid] = ow[tid];

        int wave = tid >> 6, lane = tid & 63;   // wave = class = ph*2 + pw
        int ph = wave >> 1, pw = wave & 1;

        float ch = (ph + 0.5f)*0.5f;
        float coor_h = ch - floorf(ch + 0.001f) - 0.5f;
        float cw = (pw + 0.5f)*0.5f;
        float coor_w = cw - floorf(cw + 0.001f) - 0.5f;

        float e1 = w1[lane*4+0]*0.5f + w1[lane*4+1]*0.5f
                 + w1[lane*4+2]*coor_h + w1[lane*4+3]*coor_w + b1[lane];
        sE1[wave*64 + lane] = fmaxf(e1, 0.0f);
        __syncthreads();

        float e2 = b2[lane];
        #pragma unroll 16
        for (int i = 0; i < 64; ++i) e2 += sW2[lane*65 + i] * sE1[wave*64 + i];
        e2 = fmaxf(e2, 0.0f);

        #pragma unroll
        for (int k = 0; k < 6; ++k) {
            float t = sRW[k*64 + lane] * e2;
            #pragma unroll
            for (int m = 1; m <= 32; m <<= 1) t += __shfl_xor(t, m, 64);
            if (lane == 0) {
                if (k < 4) sR[wave*4 + k] = 1.0f/(1.0f + expf(-(t + rb[k])));
                else       g_off[wave*2 + (k-4)] = t + ob[k-4];
            }
        }
        __syncthreads();

        for (int idx = tid; idx < 2048; idx += 256) {
            int cls = idx >> 9, rem = idx & 511;          // rem = o*64 + c
            float r0=sR[cls*4+0], r1=sR[cls*4+1], r2=sR[cls*4+2], r3=sR[cls*4+3];
            sWc[cls*512 + rem] =
                r0*WC[0*512+rem] + r1*WC[1*512+rem] + r2*WC[2*512+rem] + r3*WC[3*512+rem];
        }
        for (int idx = tid; idx < 2048; idx += 256) {
            int cls = idx >> 9, rem = idx & 511;          // rem = c*8 + o
            float r0=sR[cls*4+0], r1=sR[cls*4+1], r2=sR[cls*4+2], r3=sR[cls*4+3];
            sWe[cls*512 + rem] =
                r0*WE[0*512+rem] + r1*WE[1*512+rem] + r2*WE[2*512+rem] + r3*WE[3*512+rem];
        }
        __syncthreads();

        // K'[cls][c][cp] = (c==cp) + sum_o we[c][o]*wc[o][cp]  (identity folded)
        for (int idx = tid; idx < 16384; idx += 256) {
            int cls = idx >> 12, rem = idx & 4095;
            int c = rem >> 6, cp = rem & 63;
            float a = (c == cp) ? 1.0f : 0.0f;
            #pragma unroll
            for (int o = 0; o < 8; ++o)
                a += sWe[cls*512 + c*8 + o] * sWc[cls*512 + o*64 + cp];
            Kmat[idx] = f32_bf16(a);
        }
    } else {
        float* tile = smem;   // [64][65]
        int id = bid - 1;
        int b = id / PTILES, pt = id % PTILES;
        int p0 = pt * 64;
        int tlo = tid & 63, thi = tid >> 6;
        #pragma unroll
        for (int i = 0; i < 16; ++i) {
            int c = thi + i*4;
            tile[c*65 + tlo] = fused[(size_t)(b*64 + c)*LRP + p0 + tlo];
        }
        __syncthreads();
        #pragma unroll
        for (int i = 0; i < 16; ++i) {
            int p = thi + i*4;
            fused_t[(size_t)(b*LRP + p0 + p)*64 + tlo] = tile[tlo*65 + p];
        }
    }
}

// ---------------------------------------------------------------------------
// Kernel B: main. Block = 96 HR pixels of one row x 2 batches (192 items).
// Grid = 1536 = exactly 6 blocks/CU resident (24 KB LDS, launch_bounds(256,6))
// -> zero occupancy-quantization tail.
// Wave w = (batch = w>>1, parity = w&1): 48 same-class items.
// Phase 1: rolling-x bilinear gather — lane group itg owns a 12-item run,
//   each x column loaded once (26 dwordx4/lane vs 52 naive).
// sFea LDS layout: slot-major, 128 B/slot, XOR-swizzled 16B chunks
//   (chunk ^ (slot&7)) — b128 reads 2-way conflict (free), no padding.
// Phase 2: per-wave 64x64 K'_cls(A) @ feaT(B), nt-sequential to cap VGPR.
// ---------------------------------------------------------------------------
__global__ __launch_bounds__(256, 6) void main_kernel(
    const float* __restrict__ fused_t, const unsigned short* __restrict__ Kmat,
    const float* __restrict__ g_off, float* __restrict__ out)
{
    __shared__ unsigned short sFea[4*IPW*64];   // 24576 B

    int g = blockIdx.x;
    int xcd = g & 7;
    int t = g >> 3;                 // 0..191
    int q = t >> 2;                 // 0..47
    int wt = t & 3;
    int h = xcd*48 + q;
    int w0 = wt * TPX;
    int tid = threadIdx.x, wave = tid >> 6, lane = tid & 63;
    int b = wave >> 1, par = wave & 1;
    int ph = h & 1, cls = ph*2 + par;

    float off0 = g_off[cls*2 + 0];
    float off1 = g_off[cls*2 + 1];

    // y quantities: wave-uniform
    float py  = (h + 0.5f)*0.5f - 0.5f + off1;
    float y0f = floorf(py);
    float wy  = py - y0f;
    int   y0  = (int)y0f;
    float fy0 = (y0 >= 0  && y0 <= HLR_-1) ? 1.0f : 0.0f;
    float fy1 = (y0 >= -1 && y0 <= HLR_-2) ? 1.0f : 0.0f;
    int   yc0 = min(max(y0, 0), HLR_-1);
    int   yc1 = min(max(y0+1, 0), HLR_-1);
    float omwy = 1.0f - wy;

    // x: px for item i (pixel w = w0 + 2i + par) = pxb + i exactly
    float pxb  = (w0 + par + 0.5f)*0.5f - 0.5f + off0;
    float x0bf = floorf(pxb);
    float wx   = pxb - x0bf;
    int   x0b  = (int)x0bf;
    float omwx = 1.0f - wx;

    // wave-uniform corner weights with y-masks folded in
    float W00 = omwx*omwy*fy0, W01 = wx*omwy*fy0;
    float W10 = omwx*wy  *fy1, W11 = wx*wy  *fy1;

    int itg = lane >> 4;            // run owner 0..3 (12 items each)
    int cg  = lane & 15;            // channel quad

    const float* baseB = fused_t + (size_t)b * LRP * 64;
    const float* r0 = baseB + (size_t)yc0 * WLR_ * 64 + cg*4;
    const float* r1 = baseB + (size_t)yc1 * WLR_ * 64 + cg*4;
    // swizzled LDS write offset pieces
    unsigned short* sBaseW = sFea + ((wave*IPW) << 6) + (((cg & 1) << 2));
    int wchunk = cg >> 1;           // 16B chunk index 0..7

    int xs = x0b + itg*12;
    int xc = min(max(xs, 0), WLR_-1);
    f32x4 p0 = *(const f32x4*)(r0 + (size_t)xc*64);
    f32x4 p1 = *(const f32x4*)(r1 + (size_t)xc*64);
    float fxp = (xs >= 0 && xs <= WLR_-1) ? 1.0f : 0.0f;

    #pragma unroll
    for (int j = 0; j < 12; ++j) {
        int xn = xs + j + 1;
        float fxn = (xn >= 0 && xn <= WLR_-1) ? 1.0f : 0.0f;
        int xcn = min(max(xn, 0), WLR_-1);
        f32x4 c0 = *(const f32x4*)(r0 + (size_t)xcn*64);
        f32x4 c1 = *(const f32x4*)(r1 + (size_t)xcn*64);
        float a00 = W00*fxp, a01 = W01*fxn, a10 = W10*fxp, a11 = W11*fxn;
        f32x4 v = p0*a00 + c0*a01 + p1*a10 + c1*a11;
        uint2 pv;
        pv.x = pk_bf16(v[0], v[1]);
        pv.y = pk_bf16(v[2], v[3]);
        int item = itg*12 + j;
        *(uint2*)(sBaseW + (item << 6) + (((wchunk ^ (item & 7)) << 3))) = pv;
        p0 = c0; p1 = c1; fxp = fxn;
    }
    __syncthreads();

    // ---- phase 2 ----
    int lm = lane & 15, lg = lane >> 4;

    const unsigned short* Kc = Kmat + cls*4096;
    short8 Af[4][2];   // A[m][k]: m = out channel
    #pragma unroll
    for (int mt = 0; mt < 4; ++mt)
        #pragma unroll
        for (int kt = 0; kt < 2; ++kt)
            Af[mt][kt] = *(const short8*)(Kc + (mt*16 + lm)*64 + kt*32 + lg*8);

    #pragma unroll
    for (int nt = 0; nt < 3; ++nt) {
        int slot = nt*16 + lm;
        const unsigned short* sb = sFea + ((wave*IPW + slot) << 6);
        short8 B0 = *(const short8*)(sb + (((0*4 + lg) ^ (slot & 7)) << 3));
        short8 B1 = *(const short8*)(sb + (((1*4 + lg) ^ (slot & 7)) << 3));

        int wc = w0 + 2*slot + par;
        #pragma unroll
        for (int mt = 0; mt < 4; ++mt) {
            f32x4 a = {0.0f, 0.0f, 0.0f, 0.0f};
            a = __builtin_amdgcn_mfma_f32_16x16x32_bf16(Af[mt][0], B0, a, 0, 0, 0);
            a = __builtin_amdgcn_mfma_f32_16x16x32_bf16(Af[mt][1], B1, a, 0, 0, 0);
            // D[row=c][col=item]; col=lane&15, row=(lane>>4)*4+reg (m89 map)
            int c0 = mt*16 + lg*4;
            float* op = out + (((size_t)(b*64 + c0)*H_ + h)*W_ + wc);
            op[0*(size_t)(H_*W_)] = a[0];
            op[1*(size_t)(H_*W_)] = a[1];
            op[2*(size_t)(H_*W_)] = a[2];
            op[3*(size_t)(H_*W_)] = a[3];
        }
    }
}

extern "C" void kernel_launch(void* const* d_in, const int* in_sizes, int n_in,
                              void* d_out, int out_size, void* d_ws, size_t ws_size,
                              hipStream_t stream)
{
    const float* fused = (const float*)d_in[1];
    const float* WC    = (const float*)d_in[2];
    const float* WE    = (const float*)d_in[3];
    const float* w1    = (const float*)d_in[4];
    const float* b1    = (const float*)d_in[5];
    const float* w2    = (const float*)d_in[6];
    const float* b2    = (const float*)d_in[7];
    const float* rw    = (const float*)d_in[8];
    const float* rb    = (const float*)d_in[9];
    const float* ow    = (const float*)d_in[10];
    const float* ob    = (const float*)d_in[11];
    (void)in_sizes; (void)n_in; (void)out_size; (void)ws_size;

    float* ws = (float*)d_ws;
    float* fused_t = ws;
    unsigned short* Kmat = (unsigned short*)(ws + WS_K_OFF);
    float* g_off = ws + WS_OFF_OFF;
    float* o = (float*)d_out;

    hipLaunchKernelGGL(prep_kernel, dim3(1 + 2*PTILES), dim3(256), 0, stream,
                       fused, fused_t, w1, b1, w2, b2, rw, rb, ow, ob, WC, WE,
                       Kmat, g_off);
    hipLaunchKernelGGL(main_kernel, dim3(H_*NTW), dim3(256), 0, stream,
                       fused_t, Kmat, g_off, o);
}